// Round 2
// baseline (114.005 us; speedup 1.0000x reference)
//
#include <hip/hip_runtime.h>

// Soft VQ encoding, fused bf16-MFMA implementation. Round 10.
//   X:(8,16384,128) fp32, C:(128,128) fp32, S:(128) fp32 -> E:(8,128,128) fp32
// r9 post-mortem: -1.6us (115->113.4). Confirms decomposition S1: timed window
// = 2x 256MiB poison fills (~82us, fixed) + vq_main (~23us) + vq_reduce (~8us).
// Kernel HBM floor ~15.5us; LDS pipe in vq_main ~12us/CU. The fight is the
// ~31us kernel share.
// r10 changes vs r9:
//  (1) FULL next-chunk prefetch: raw[8] (all 8 float4 = whole 128-d row pair)
//      issued right after barrier A, not split ks0/1-prefetch + ks2/3-at-top.
//      Kills the ~900cy HBM-latency stall at each chunk top (ks2/3 were
//      issued there and consumed ~20 instrs later, in a window no other
//      phase overlaps). +16 arch VGPRs live through mm2; spill tripwire =
//      WRITE_SIZE above 262144KB baseline / regression -> revert.
//  (2) exp2 fold: sST premultiplied by log2(e) at prologue; softmax uses
//      __builtin_amdgcn_exp2f directly (v_exp_f32 computes 2^x). Removes 32
//      v_mul/wave-chunk from the exp dependency chain. Same math to 1 ulp.
//  (3) vq_reduce: #pragma unroll 32 -> ~32KB/CU loads in flight (need
//      ~22.5KB to cover ~900cy at fair-share 25B/cyc/CU).

#define NN   16384
#define ND   128
#define NK   128
#define NC   64        // rows per chunk
#define TT   4         // chunks per block
#define BPB  64        // blocks per batch (grid = 8*BPB = 512)
#define CBP  136       // sCb row stride (bf16 elems), 272B -> b128-aligned, 2-way banks
#define XTP  72        // X^T LDS row stride, 144B (stride%32banks=4 -> spreads rows)
#define ATP  72        // A^T LDS row stride, 144B
#define LOG2E 1.4426950408889634f

typedef __bf16 bf16x8 __attribute__((ext_vector_type(8)));
typedef float  f32x4  __attribute__((ext_vector_type(4)));

union CU  { __bf16 b[8]; unsigned short u[8]; bf16x8 v; };
union HH4 { __bf16 b[4]; ushort4 s; };

__device__ __forceinline__ float bf2f(unsigned short u) {
    return __uint_as_float(((unsigned int)u) << 16);
}

// ---------------- kernel 1: fused main ----------------
__global__ __launch_bounds__(256, 2) void vq_main(
    const float* __restrict__ Xg, const float* __restrict__ Cg,
    const float* __restrict__ Sg, unsigned short* __restrict__ Pg)
{
    __shared__ __align__(16) unsigned short sCb[NK * CBP];   // 34816 B
    __shared__ __align__(16) unsigned short sXT[ND * XTP];   // 18432 B
    __shared__ __align__(16) unsigned short sAt[NK * ATP];   // 18432 B
    __shared__ __align__(16) float2 sST[NK];                 // 1 KB
    __shared__ __align__(16) float  sC2[NK];                 // 512 B

    const int tid  = threadIdx.x;
    const int lane = tid & 63;
    const int wave = tid >> 6;
    const int l15  = lane & 15;
    const int quad = lane >> 4;
    const int bid  = blockIdx.x;
    const int b    = bid >> 6;        // batch
    const int bg   = bid & (BPB - 1); // block-in-batch

    const float* Xb = Xg + (size_t)b * (NN * ND);
    const int rloc = wave * 16 + l15;   // chunk-local row this lane stages

    // software pipeline: raw[] holds the FULL next chunk row (8 float4)
    float4 raw[8];
    {
        const float* rp0 = Xb + (size_t)(bg * TT * NC + rloc) * ND;
        #pragma unroll
        for (int ks = 0; ks < 4; ++ks) {
            raw[ks * 2]     = *reinterpret_cast<const float4*>(rp0 + ks * 32 + quad * 8);
            raw[ks * 2 + 1] = *reinterpret_cast<const float4*>(rp0 + ks * 32 + quad * 8 + 4);
        }
    }

    // ---- prologue: stage C -> bf16 LDS, C2 row sums, ST = {S*log2e, S*C2*log2e} ----
    #pragma unroll
    for (int it = 0; it < 16; ++it) {
        int flat = it * 256 + tid;
        int row  = flat >> 5;          // 0..127
        int c4   = flat & 31;
        float4 v = reinterpret_cast<const float4*>(Cg)[row * 32 + c4];
        HH4 h;
        h.b[0] = (__bf16)v.x; h.b[1] = (__bf16)v.y;
        h.b[2] = (__bf16)v.z; h.b[3] = (__bf16)v.w;
        *reinterpret_cast<ushort4*>(&sCb[row * CBP + c4 * 4]) = h.s;
        float ss = v.x*v.x + v.y*v.y + v.z*v.z + v.w*v.w;
        ss += __shfl_xor(ss, 1);
        ss += __shfl_xor(ss, 2);
        ss += __shfl_xor(ss, 4);
        ss += __shfl_xor(ss, 8);
        ss += __shfl_xor(ss, 16);
        if ((lane & 31) == 0) sC2[row] = ss;
    }
    __syncthreads();
    if (tid < NK) {
        float s = Sg[tid] * LOG2E;
        sST[tid] = make_float2(s, s * sC2[tid]);
    }
    // (barrier (A) of chunk 0 orders sST before first softmax use)

    f32x4 eacc[2][8];
    #pragma unroll
    for (int i = 0; i < 2; ++i)
        #pragma unroll
        for (int j = 0; j < 8; ++j)
            eacc[i][j] = (f32x4){0.f, 0.f, 0.f, 0.f};
    f32x4 cntacc[2];
    cntacc[0] = (f32x4){0.f, 0.f, 0.f, 0.f};
    cntacc[1] = (f32x4){0.f, 0.f, 0.f, 0.f};

    CU one8;
    #pragma unroll
    for (int j = 0; j < 8; ++j) one8.u[j] = 0x3F80;  // bf16 1.0

    #pragma unroll 1
    for (int t = 0; t < TT; ++t) {
        const int chunk = bg * TT + t;
        const float* rp = Xb + (size_t)(chunk * NC + rloc) * ND;

        // ---- convert full row from raw[] (no global loads at chunk top) ----
        CU cu[4];
        float x2 = 0.f;
        #pragma unroll
        for (int ks = 0; ks < 4; ++ks) {
            float4 va = raw[ks * 2], vb = raw[ks * 2 + 1];
            x2 += va.x*va.x + va.y*va.y + va.z*va.z + va.w*va.w;
            x2 += vb.x*vb.x + vb.y*vb.y + vb.z*vb.z + vb.w*vb.w;
            cu[ks].b[0] = (__bf16)va.x; cu[ks].b[1] = (__bf16)va.y;
            cu[ks].b[2] = (__bf16)va.z; cu[ks].b[3] = (__bf16)va.w;
            cu[ks].b[4] = (__bf16)vb.x; cu[ks].b[5] = (__bf16)vb.y;
            cu[ks].b[6] = (__bf16)vb.z; cu[ks].b[7] = (__bf16)vb.w;
        }
        x2 += __shfl_xor(x2, 16);
        x2 += __shfl_xor(x2, 32);       // full X2 of row (chunk*64 + rloc)

        __syncthreads();                // (A) prev chunk's matmul2 reads done

        // ---- prefetch ENTIRE next chunk row (in flight across mm1+sm+mm2) ----
        if (t + 1 < TT) {
            const float* rpn = rp + (size_t)NC * ND;
            #pragma unroll
            for (int ks = 0; ks < 4; ++ks) {
                raw[ks * 2]     = *reinterpret_cast<const float4*>(rpn + ks * 32 + quad * 8);
                raw[ks * 2 + 1] = *reinterpret_cast<const float4*>(rpn + ks * 32 + quad * 8 + 4);
            }
        }

        // ---- scatter X^T (swizzled to dodge bank conflicts) ----
        #pragma unroll
        for (int ks = 0; ks < 4; ++ks) {
            #pragma unroll
            for (int j = 0; j < 8; ++j) {
                int d  = ks * 32 + quad * 8 + j;
                int rs = rloc ^ (((d >> 3) & 3) << 3);
                sXT[d * XTP + rs] = cu[ks].u[j];
            }
        }

        // ---- matmul1 (swapped): D^T[n][cw] = X x C^T ----
        // A = cu (lane's own row, registers, free); B = sCb bytes as C^T-frags.
        // D-frag: lane holds (n = quad*4+r, cw = mt*16+l15).
        f32x4 dacc[8];
        #pragma unroll
        for (int mt = 0; mt < 8; ++mt) {
            f32x4 acc = (f32x4){0.f, 0.f, 0.f, 0.f};
            #pragma unroll
            for (int ks = 0; ks < 4; ++ks) {
                bf16x8 cf = *reinterpret_cast<const bf16x8*>(
                    &sCb[(mt * 16 + l15) * CBP + ks * 32 + quad * 8]);
                acc = __builtin_amdgcn_mfma_f32_16x16x32_bf16(cu[ks].v, cf, acc, 0, 0, 0);
            }
            dacc[mt] = acc;
        }

        // ---- softmax over cw, NO max pass (S<=0 => D<=0 => exp in (0,1]) ----
        // lane needs x2 of rows wave*16 + quad*4 + r (held by lanes l15=quad*4+r)
        float x2r0 = __shfl(x2, quad * 4 + 0);
        float x2r1 = __shfl(x2, quad * 4 + 1);
        float x2r2 = __shfl(x2, quad * 4 + 2);
        float x2r3 = __shfl(x2, quad * 4 + 3);
        float ls0 = 0.f, ls1 = 0.f, ls2 = 0.f, ls3 = 0.f;
        #pragma unroll
        for (int mt = 0; mt < 8; ++mt) {
            float2 sv = sST[mt * 16 + l15];   // broadcast across quads, conflict-free
            float e0 = __builtin_amdgcn_exp2f(sv.x * fmaf(-2.f, dacc[mt][0], x2r0) + sv.y);
            float e1 = __builtin_amdgcn_exp2f(sv.x * fmaf(-2.f, dacc[mt][1], x2r1) + sv.y);
            float e2 = __builtin_amdgcn_exp2f(sv.x * fmaf(-2.f, dacc[mt][2], x2r2) + sv.y);
            float e3 = __builtin_amdgcn_exp2f(sv.x * fmaf(-2.f, dacc[mt][3], x2r3) + sv.y);
            dacc[mt][0] = e0; dacc[mt][1] = e1;
            dacc[mt][2] = e2; dacc[mt][3] = e3;
            ls0 += e0; ls1 += e1; ls2 += e2; ls3 += e3;
        }
        // reduce over cw: mt handled above, l15 axis via xor-tree (quads are
        // distinct n, must NOT mix -> masks 1,2,4,8 only)
        #pragma unroll
        for (int sh = 1; sh < 16; sh <<= 1) {
            ls0 += __shfl_xor(ls0, sh);
            ls1 += __shfl_xor(ls1, sh);
            ls2 += __shfl_xor(ls2, sh);
            ls3 += __shfl_xor(ls3, sh);
        }
        const float inv0 = 1.0f / ls0, inv1 = 1.0f / ls1;
        const float inv2 = 1.0f / ls2, inv3 = 1.0f / ls3;

        // ---- A -> LDS: 4 consecutive n per lane -> packed ds_write_b64 ----
        #pragma unroll
        for (int mt = 0; mt < 8; ++mt) {
            HH4 h;
            h.b[0] = (__bf16)(dacc[mt][0] * inv0);
            h.b[1] = (__bf16)(dacc[mt][1] * inv1);
            h.b[2] = (__bf16)(dacc[mt][2] * inv2);
            h.b[3] = (__bf16)(dacc[mt][3] * inv3);
            *reinterpret_cast<ushort4*>(
                &sAt[(mt * 16 + l15) * ATP + wave * 16 + quad * 4]) = h.s;
        }

        __syncthreads();                // (B) X^T and A^T visible to all waves

        // ---- matmul2: E[cw][d] += A x X, dt-outer so each b-frag is read
        //      ONCE and reused for both mt2 (b128 reads 32 -> 16/wave/chunk).
        bf16x8 a0[2], a1[2];
        #pragma unroll
        for (int mt2 = 0; mt2 < 2; ++mt2) {
            const int cwrow = wave * 32 + mt2 * 16 + l15;
            a0[mt2] = *reinterpret_cast<const bf16x8*>(&sAt[cwrow * ATP + quad * 8]);
            a1[mt2] = *reinterpret_cast<const bf16x8*>(&sAt[cwrow * ATP + 32 + quad * 8]);
            // count[cw] += sum_n A[cw][n]: B = ones -> D[row][col] indep of col
            cntacc[mt2] = __builtin_amdgcn_mfma_f32_16x16x32_bf16(a0[mt2], one8.v, cntacc[mt2], 0, 0, 0);
            cntacc[mt2] = __builtin_amdgcn_mfma_f32_16x16x32_bf16(a1[mt2], one8.v, cntacc[mt2], 0, 0, 0);
        }
        #pragma unroll
        for (int dt = 0; dt < 8; ++dt) {
            const int drow = dt * 16 + l15;
            const int sw = ((drow >> 3) & 3) << 3;
            const unsigned short* xp = &sXT[drow * XTP];
            bf16x8 b0 = *reinterpret_cast<const bf16x8*>(&xp[(quad * 8) ^ sw]);
            bf16x8 b1 = *reinterpret_cast<const bf16x8*>(&xp[(32 + quad * 8) ^ sw]);
            #pragma unroll
            for (int mt2 = 0; mt2 < 2; ++mt2) {
                eacc[mt2][dt] = __builtin_amdgcn_mfma_f32_16x16x32_bf16(a0[mt2], b0, eacc[mt2][dt], 0, 0, 0);
                eacc[mt2][dt] = __builtin_amdgcn_mfma_f32_16x16x32_bf16(a1[mt2], b1, eacc[mt2][dt], 0, 0, 0);
            }
        }
    }

    // ---- epilogue: bf16 partial (E_part - count*C) to private ws slice ----
    // cntacc[mt2][r] holds count for cw = wave*32+mt2*16+quad*4+r (all l15 lanes)
    unsigned short* P = Pg + (size_t)bid * (NK * ND);
    #pragma unroll
    for (int mt2 = 0; mt2 < 2; ++mt2) {
        #pragma unroll
        for (int r = 0; r < 4; ++r) {
            const int cw = wave * 32 + mt2 * 16 + quad * 4 + r;
            const float cc = cntacc[mt2][r];
            const float* crow = Cg + cw * ND;
            #pragma unroll
            for (int dt = 0; dt < 8; ++dt) {
                const int d = dt * 16 + l15;
                *reinterpret_cast<__bf16*>(&P[cw * ND + d]) =
                    (__bf16)(eacc[mt2][dt][r] - cc * crow[d]);
            }
        }
    }
}

// ---------------- kernel 2: partial reduction ----------------
// r10: thread-per-float2, 4 waves/CU, unroll 32 -> ~32KB/CU loads in flight.
__global__ __launch_bounds__(128) void vq_reduce(
    const unsigned short* __restrict__ Pg, float* __restrict__ Eg)
{
    const int g  = blockIdx.x * 128 + threadIdx.x;   // 0..65535
    const int b  = g >> 13;                          // 8192 float2 per batch
    const int i2 = g & 8191;
    const unsigned short* base = Pg + (size_t)(b * BPB) * (NK * ND) + i2 * 2;
    float a0 = 0.f, a1 = 0.f;
    #pragma unroll 32
    for (int j = 0; j < BPB; ++j) {
        ushort2 v = *reinterpret_cast<const ushort2*>(base + (size_t)j * (NK * ND));
        a0 += bf2f(v.x); a1 += bf2f(v.y);
    }
    float2 o; o.x = a0; o.y = a1;
    *reinterpret_cast<float2*>(Eg + (size_t)b * (NK * ND) + i2 * 2) = o;
}

extern "C" void kernel_launch(void* const* d_in, const int* in_sizes, int n_in,
                              void* d_out, int out_size, void* d_ws, size_t ws_size,
                              hipStream_t stream) {
    const float* X = (const float*)d_in[0];
    const float* C = (const float*)d_in[1];
    const float* S = (const float*)d_in[2];
    float* E = (float*)d_out;
    (void)n_in; (void)in_sizes; (void)out_size; (void)ws_size;

    // ws layout: bf16 partials, 512 * 16384 u16 = 16 MiB.
    unsigned short* P = (unsigned short*)d_ws;

    hipLaunchKernelGGL(vq_main,   dim3(512), dim3(256), 0, stream, X, C, S, P);
    hipLaunchKernelGGL(vq_reduce, dim3(512), dim3(128), 0, stream, P, E);
}

// Round 3
// 114.004 us; speedup vs baseline: 1.0000x; 1.0000x over previous
//
#include <hip/hip_runtime.h>

// Soft VQ encoding, fused bf16-MFMA implementation. Round 11.
//   X:(8,16384,128) fp32, C:(128,128) fp32, S:(128) fp32 -> E:(8,128,128) fp32
// r10 post-mortem: null (+0.6us, noise). Full X-prefetch / exp2 / unroll-32
// bought nothing -> chunk-top latency was NOT the limiter; WRITE_SIZE flat at
// 262144KB (no spill). Remaining theory: barrier-window convoys. vq_main's
// [A]->[B] window held scatter+mm1+softmax+sAtW (~900+cy serialized across
// 8 phase-locked waves/CU); LDS pipe ~50% idle.
// r11 (single change): REORDER. mm1+softmax depend only on regs (cu,x2) and
// never-rewritten LDS (sCb,sST) -- hoist them BEFORE barrier [A]; window
// [A]->[B] shrinks to scatter + 8 sAt b64 stores (~240cy). A-normalize+pack
// to bf16 regs (hh[8]) also pre-[A]. Extra prologue barrier after sST write
// (softmax(0) now reads sST before [A]).
//   predicted: dur 114 -> 110-112; WRITE_SIZE flat (spill tripwire);
//   conflicts flat; absmax flat. Null => kernels near structural floor.

#define NN   16384
#define ND   128
#define NK   128
#define NC   64        // rows per chunk
#define TT   4         // chunks per block
#define BPB  64        // blocks per batch (grid = 8*BPB = 512)
#define CBP  136       // sCb row stride (bf16 elems), 272B -> b128-aligned, 2-way banks
#define XTP  72        // X^T LDS row stride, 144B (stride%32banks=4 -> spreads rows)
#define ATP  72        // A^T LDS row stride, 144B
#define LOG2E 1.4426950408889634f

typedef __bf16 bf16x8 __attribute__((ext_vector_type(8)));
typedef float  f32x4  __attribute__((ext_vector_type(4)));

union CU  { __bf16 b[8]; unsigned short u[8]; bf16x8 v; };
union HH4 { __bf16 b[4]; ushort4 s; };

__device__ __forceinline__ float bf2f(unsigned short u) {
    return __uint_as_float(((unsigned int)u) << 16);
}

// ---------------- kernel 1: fused main ----------------
__global__ __launch_bounds__(256, 2) void vq_main(
    const float* __restrict__ Xg, const float* __restrict__ Cg,
    const float* __restrict__ Sg, unsigned short* __restrict__ Pg)
{
    __shared__ __align__(16) unsigned short sCb[NK * CBP];   // 34816 B
    __shared__ __align__(16) unsigned short sXT[ND * XTP];   // 18432 B
    __shared__ __align__(16) unsigned short sAt[NK * ATP];   // 18432 B
    __shared__ __align__(16) float2 sST[NK];                 // 1 KB
    __shared__ __align__(16) float  sC2[NK];                 // 512 B

    const int tid  = threadIdx.x;
    const int lane = tid & 63;
    const int wave = tid >> 6;
    const int l15  = lane & 15;
    const int quad = lane >> 4;
    const int bid  = blockIdx.x;
    const int b    = bid >> 6;        // batch
    const int bg   = bid & (BPB - 1); // block-in-batch

    const float* Xb = Xg + (size_t)b * (NN * ND);
    const int rloc = wave * 16 + l15;   // chunk-local row this lane stages

    // software pipeline: raw[] holds the FULL next chunk row (8 float4)
    float4 raw[8];
    {
        const float* rp0 = Xb + (size_t)(bg * TT * NC + rloc) * ND;
        #pragma unroll
        for (int ks = 0; ks < 4; ++ks) {
            raw[ks * 2]     = *reinterpret_cast<const float4*>(rp0 + ks * 32 + quad * 8);
            raw[ks * 2 + 1] = *reinterpret_cast<const float4*>(rp0 + ks * 32 + quad * 8 + 4);
        }
    }

    // ---- prologue: stage C -> bf16 LDS, C2 row sums, ST = {S*log2e, S*C2*log2e} ----
    #pragma unroll
    for (int it = 0; it < 16; ++it) {
        int flat = it * 256 + tid;
        int row  = flat >> 5;          // 0..127
        int c4   = flat & 31;
        float4 v = reinterpret_cast<const float4*>(Cg)[row * 32 + c4];
        HH4 h;
        h.b[0] = (__bf16)v.x; h.b[1] = (__bf16)v.y;
        h.b[2] = (__bf16)v.z; h.b[3] = (__bf16)v.w;
        *reinterpret_cast<ushort4*>(&sCb[row * CBP + c4 * 4]) = h.s;
        float ss = v.x*v.x + v.y*v.y + v.z*v.z + v.w*v.w;
        ss += __shfl_xor(ss, 1);
        ss += __shfl_xor(ss, 2);
        ss += __shfl_xor(ss, 4);
        ss += __shfl_xor(ss, 8);
        ss += __shfl_xor(ss, 16);
        if ((lane & 31) == 0) sC2[row] = ss;
    }
    __syncthreads();
    if (tid < NK) {
        float s = Sg[tid] * LOG2E;
        sST[tid] = make_float2(s, s * sC2[tid]);
    }
    __syncthreads();   // sST visible before first (pre-[A]) softmax use

    f32x4 eacc[2][8];
    #pragma unroll
    for (int i = 0; i < 2; ++i)
        #pragma unroll
        for (int j = 0; j < 8; ++j)
            eacc[i][j] = (f32x4){0.f, 0.f, 0.f, 0.f};
    f32x4 cntacc[2];
    cntacc[0] = (f32x4){0.f, 0.f, 0.f, 0.f};
    cntacc[1] = (f32x4){0.f, 0.f, 0.f, 0.f};

    CU one8;
    #pragma unroll
    for (int j = 0; j < 8; ++j) one8.u[j] = 0x3F80;  // bf16 1.0

    #pragma unroll 1
    for (int t = 0; t < TT; ++t) {
        const int chunk = bg * TT + t;
        const float* rp = Xb + (size_t)(chunk * NC + rloc) * ND;

        // ---- convert full row from raw[] (registers only) ----
        CU cu[4];
        float x2 = 0.f;
        #pragma unroll
        for (int ks = 0; ks < 4; ++ks) {
            float4 va = raw[ks * 2], vb = raw[ks * 2 + 1];
            x2 += va.x*va.x + va.y*va.y + va.z*va.z + va.w*va.w;
            x2 += vb.x*vb.x + vb.y*vb.y + vb.z*vb.z + vb.w*vb.w;
            cu[ks].b[0] = (__bf16)va.x; cu[ks].b[1] = (__bf16)va.y;
            cu[ks].b[2] = (__bf16)va.z; cu[ks].b[3] = (__bf16)va.w;
            cu[ks].b[4] = (__bf16)vb.x; cu[ks].b[5] = (__bf16)vb.y;
            cu[ks].b[6] = (__bf16)vb.z; cu[ks].b[7] = (__bf16)vb.w;
        }
        x2 += __shfl_xor(x2, 16);
        x2 += __shfl_xor(x2, 32);       // full X2 of row (chunk*64 + rloc)

        // ---- prefetch ENTIRE next chunk row (earliest possible issue) ----
        if (t + 1 < TT) {
            const float* rpn = rp + (size_t)NC * ND;
            #pragma unroll
            for (int ks = 0; ks < 4; ++ks) {
                raw[ks * 2]     = *reinterpret_cast<const float4*>(rpn + ks * 32 + quad * 8);
                raw[ks * 2 + 1] = *reinterpret_cast<const float4*>(rpn + ks * 32 + quad * 8 + 4);
            }
        }

        // ---- matmul1 (PRE-barrier: needs only cu regs + sCb/sST, never
        //      rewritten): D^T[n][cw] = X x C^T.
        //      D-frag: lane holds (n = quad*4+r, cw = mt*16+l15).
        f32x4 dacc[8];
        #pragma unroll
        for (int mt = 0; mt < 8; ++mt) {
            f32x4 acc = (f32x4){0.f, 0.f, 0.f, 0.f};
            #pragma unroll
            for (int ks = 0; ks < 4; ++ks) {
                bf16x8 cf = *reinterpret_cast<const bf16x8*>(
                    &sCb[(mt * 16 + l15) * CBP + ks * 32 + quad * 8]);
                acc = __builtin_amdgcn_mfma_f32_16x16x32_bf16(cu[ks].v, cf, acc, 0, 0, 0);
            }
            dacc[mt] = acc;
        }

        // ---- softmax over cw (pre-barrier), NO max pass (S<=0 => exp<=1) ----
        float x2r0 = __shfl(x2, quad * 4 + 0);
        float x2r1 = __shfl(x2, quad * 4 + 1);
        float x2r2 = __shfl(x2, quad * 4 + 2);
        float x2r3 = __shfl(x2, quad * 4 + 3);
        float ls0 = 0.f, ls1 = 0.f, ls2 = 0.f, ls3 = 0.f;
        #pragma unroll
        for (int mt = 0; mt < 8; ++mt) {
            float2 sv = sST[mt * 16 + l15];   // broadcast across quads, conflict-free
            float e0 = __builtin_amdgcn_exp2f(sv.x * fmaf(-2.f, dacc[mt][0], x2r0) + sv.y);
            float e1 = __builtin_amdgcn_exp2f(sv.x * fmaf(-2.f, dacc[mt][1], x2r1) + sv.y);
            float e2 = __builtin_amdgcn_exp2f(sv.x * fmaf(-2.f, dacc[mt][2], x2r2) + sv.y);
            float e3 = __builtin_amdgcn_exp2f(sv.x * fmaf(-2.f, dacc[mt][3], x2r3) + sv.y);
            dacc[mt][0] = e0; dacc[mt][1] = e1;
            dacc[mt][2] = e2; dacc[mt][3] = e3;
            ls0 += e0; ls1 += e1; ls2 += e2; ls3 += e3;
        }
        // reduce over cw: l15 axis via xor-tree (masks 1,2,4,8 only)
        #pragma unroll
        for (int sh = 1; sh < 16; sh <<= 1) {
            ls0 += __shfl_xor(ls0, sh);
            ls1 += __shfl_xor(ls1, sh);
            ls2 += __shfl_xor(ls2, sh);
            ls3 += __shfl_xor(ls3, sh);
        }
        const float inv0 = 1.0f / ls0, inv1 = 1.0f / ls1;
        const float inv2 = 1.0f / ls2, inv3 = 1.0f / ls3;

        // ---- normalize + pack A to bf16 regs (pre-barrier; hh = 8 ushort4) ----
        HH4 hh[8];
        #pragma unroll
        for (int mt = 0; mt < 8; ++mt) {
            hh[mt].b[0] = (__bf16)(dacc[mt][0] * inv0);
            hh[mt].b[1] = (__bf16)(dacc[mt][1] * inv1);
            hh[mt].b[2] = (__bf16)(dacc[mt][2] * inv2);
            hh[mt].b[3] = (__bf16)(dacc[mt][3] * inv3);
        }

        __syncthreads();                // (A) prev chunk's matmul2 reads done

        // ---- minimal [A]->[B] window: scatter X^T + store A^T only ----
        #pragma unroll
        for (int ks = 0; ks < 4; ++ks) {
            #pragma unroll
            for (int j = 0; j < 8; ++j) {
                int d  = ks * 32 + quad * 8 + j;
                int rs = rloc ^ (((d >> 3) & 3) << 3);
                sXT[d * XTP + rs] = cu[ks].u[j];
            }
        }
        #pragma unroll
        for (int mt = 0; mt < 8; ++mt) {
            *reinterpret_cast<ushort4*>(
                &sAt[(mt * 16 + l15) * ATP + wave * 16 + quad * 4]) = hh[mt].s;
        }

        __syncthreads();                // (B) X^T and A^T visible to all waves

        // ---- matmul2: E[cw][d] += A x X, dt-outer so each b-frag is read
        //      ONCE and reused for both mt2 (b128 reads 32 -> 16/wave/chunk).
        bf16x8 a0[2], a1[2];
        #pragma unroll
        for (int mt2 = 0; mt2 < 2; ++mt2) {
            const int cwrow = wave * 32 + mt2 * 16 + l15;
            a0[mt2] = *reinterpret_cast<const bf16x8*>(&sAt[cwrow * ATP + quad * 8]);
            a1[mt2] = *reinterpret_cast<const bf16x8*>(&sAt[cwrow * ATP + 32 + quad * 8]);
            // count[cw] += sum_n A[cw][n]: B = ones -> D[row][col] indep of col
            cntacc[mt2] = __builtin_amdgcn_mfma_f32_16x16x32_bf16(a0[mt2], one8.v, cntacc[mt2], 0, 0, 0);
            cntacc[mt2] = __builtin_amdgcn_mfma_f32_16x16x32_bf16(a1[mt2], one8.v, cntacc[mt2], 0, 0, 0);
        }
        #pragma unroll
        for (int dt = 0; dt < 8; ++dt) {
            const int drow = dt * 16 + l15;
            const int sw = ((drow >> 3) & 3) << 3;
            const unsigned short* xp = &sXT[drow * XTP];
            bf16x8 b0 = *reinterpret_cast<const bf16x8*>(&xp[(quad * 8) ^ sw]);
            bf16x8 b1 = *reinterpret_cast<const bf16x8*>(&xp[(32 + quad * 8) ^ sw]);
            #pragma unroll
            for (int mt2 = 0; mt2 < 2; ++mt2) {
                eacc[mt2][dt] = __builtin_amdgcn_mfma_f32_16x16x32_bf16(a0[mt2], b0, eacc[mt2][dt], 0, 0, 0);
                eacc[mt2][dt] = __builtin_amdgcn_mfma_f32_16x16x32_bf16(a1[mt2], b1, eacc[mt2][dt], 0, 0, 0);
            }
        }
    }

    // ---- epilogue: bf16 partial (E_part - count*C) to private ws slice ----
    // cntacc[mt2][r] holds count for cw = wave*32+mt2*16+quad*4+r (all l15 lanes)
    unsigned short* P = Pg + (size_t)bid * (NK * ND);
    #pragma unroll
    for (int mt2 = 0; mt2 < 2; ++mt2) {
        #pragma unroll
        for (int r = 0; r < 4; ++r) {
            const int cw = wave * 32 + mt2 * 16 + quad * 4 + r;
            const float cc = cntacc[mt2][r];
            const float* crow = Cg + cw * ND;
            #pragma unroll
            for (int dt = 0; dt < 8; ++dt) {
                const int d = dt * 16 + l15;
                *reinterpret_cast<__bf16*>(&P[cw * ND + d]) =
                    (__bf16)(eacc[mt2][dt][r] - cc * crow[d]);
            }
        }
    }
}

// ---------------- kernel 2: partial reduction ----------------
// thread-per-float2, 4 waves/CU, unroll 32 -> ~32KB/CU loads in flight.
__global__ __launch_bounds__(128) void vq_reduce(
    const unsigned short* __restrict__ Pg, float* __restrict__ Eg)
{
    const int g  = blockIdx.x * 128 + threadIdx.x;   // 0..65535
    const int b  = g >> 13;                          // 8192 float2 per batch
    const int i2 = g & 8191;
    const unsigned short* base = Pg + (size_t)(b * BPB) * (NK * ND) + i2 * 2;
    float a0 = 0.f, a1 = 0.f;
    #pragma unroll 32
    for (int j = 0; j < BPB; ++j) {
        ushort2 v = *reinterpret_cast<const ushort2*>(base + (size_t)j * (NK * ND));
        a0 += bf2f(v.x); a1 += bf2f(v.y);
    }
    float2 o; o.x = a0; o.y = a1;
    *reinterpret_cast<float2*>(Eg + (size_t)b * (NK * ND) + i2 * 2) = o;
}

extern "C" void kernel_launch(void* const* d_in, const int* in_sizes, int n_in,
                              void* d_out, int out_size, void* d_ws, size_t ws_size,
                              hipStream_t stream) {
    const float* X = (const float*)d_in[0];
    const float* C = (const float*)d_in[1];
    const float* S = (const float*)d_in[2];
    float* E = (float*)d_out;
    (void)n_in; (void)in_sizes; (void)out_size; (void)ws_size;

    // ws layout: bf16 partials, 512 * 16384 u16 = 16 MiB.
    unsigned short* P = (unsigned short*)d_ws;

    hipLaunchKernelGGL(vq_main,   dim3(512), dim3(256), 0, stream, X, C, S, P);
    hipLaunchKernelGGL(vq_reduce, dim3(512), dim3(128), 0, stream, P, E);
}

// Round 4
// 113.565 us; speedup vs baseline: 1.0039x; 1.0039x over previous
//
#include <hip/hip_runtime.h>

// Soft VQ encoding, fused bf16-MFMA implementation. Round 12.
//   X:(8,16384,128) fp32, C:(128,128) fp32, S:(128) fp32 -> E:(8,128,128) fp32
// r11 post-mortem: exactly null (114.005->114.004). Barrier-window convoy
// theory dead: [A]->[B] shrink 900->240cy changed nothing. With r10 also null,
// intra-loop schedule is NOT the limiter (cross-block overlap or steady-state
// LDS+HBM overlap already absorbs it).
// r12 (single change): HALVE THE GRID. 256 blocks x TT=8 instead of 512 x
// TT=4. Partial-workspace round-trip halves: P write 16.8->8.4 MB, P read
// 16.8->8.4 MB (~1.5-2.6us saved depending on L3 vs HBM service). Per-block
// LDS/waves/inner-loop byte-identical; prologue amortizes 2x. This also
// A/B-tests the cross-block-overlap hypothesis: 1 block/CU now -- if the
// r10/r11 flats were due to 2-block overlap hiding everything, this round
// REGRESSES (+2-4us) and localizes the mechanism; revert next round.
//   predicted: 111.5 +/- 1.5 (win) or >=116 (overlap-was-load-bearing).
//   WRITE_SIZE flat 262144KB; absmax flat 128.

#define NN   16384
#define ND   128
#define NK   128
#define NC   64        // rows per chunk
#define TT   8         // chunks per block (r12: was 4)
#define BPB  32        // blocks per batch (r12: was 64; grid = 8*BPB = 256)
#define CBP  136       // sCb row stride (bf16 elems), 272B -> b128-aligned, 2-way banks
#define XTP  72        // X^T LDS row stride, 144B (stride%32banks=4 -> spreads rows)
#define ATP  72        // A^T LDS row stride, 144B
#define LOG2E 1.4426950408889634f

typedef __bf16 bf16x8 __attribute__((ext_vector_type(8)));
typedef float  f32x4  __attribute__((ext_vector_type(4)));

union CU  { __bf16 b[8]; unsigned short u[8]; bf16x8 v; };
union HH4 { __bf16 b[4]; ushort4 s; };

__device__ __forceinline__ float bf2f(unsigned short u) {
    return __uint_as_float(((unsigned int)u) << 16);
}

// ---------------- kernel 1: fused main ----------------
__global__ __launch_bounds__(256, 2) void vq_main(
    const float* __restrict__ Xg, const float* __restrict__ Cg,
    const float* __restrict__ Sg, unsigned short* __restrict__ Pg)
{
    __shared__ __align__(16) unsigned short sCb[NK * CBP];   // 34816 B
    __shared__ __align__(16) unsigned short sXT[ND * XTP];   // 18432 B
    __shared__ __align__(16) unsigned short sAt[NK * ATP];   // 18432 B
    __shared__ __align__(16) float2 sST[NK];                 // 1 KB
    __shared__ __align__(16) float  sC2[NK];                 // 512 B

    const int tid  = threadIdx.x;
    const int lane = tid & 63;
    const int wave = tid >> 6;
    const int l15  = lane & 15;
    const int quad = lane >> 4;
    const int bid  = blockIdx.x;
    const int b    = bid >> 5;        // batch (BPB=32)
    const int bg   = bid & (BPB - 1); // block-in-batch

    const float* Xb = Xg + (size_t)b * (NN * ND);
    const int rloc = wave * 16 + l15;   // chunk-local row this lane stages

    // software pipeline: raw[] holds the FULL next chunk row (8 float4)
    float4 raw[8];
    {
        const float* rp0 = Xb + (size_t)(bg * TT * NC + rloc) * ND;
        #pragma unroll
        for (int ks = 0; ks < 4; ++ks) {
            raw[ks * 2]     = *reinterpret_cast<const float4*>(rp0 + ks * 32 + quad * 8);
            raw[ks * 2 + 1] = *reinterpret_cast<const float4*>(rp0 + ks * 32 + quad * 8 + 4);
        }
    }

    // ---- prologue: stage C -> bf16 LDS, C2 row sums, ST = {S*log2e, S*C2*log2e} ----
    #pragma unroll
    for (int it = 0; it < 16; ++it) {
        int flat = it * 256 + tid;
        int row  = flat >> 5;          // 0..127
        int c4   = flat & 31;
        float4 v = reinterpret_cast<const float4*>(Cg)[row * 32 + c4];
        HH4 h;
        h.b[0] = (__bf16)v.x; h.b[1] = (__bf16)v.y;
        h.b[2] = (__bf16)v.z; h.b[3] = (__bf16)v.w;
        *reinterpret_cast<ushort4*>(&sCb[row * CBP + c4 * 4]) = h.s;
        float ss = v.x*v.x + v.y*v.y + v.z*v.z + v.w*v.w;
        ss += __shfl_xor(ss, 1);
        ss += __shfl_xor(ss, 2);
        ss += __shfl_xor(ss, 4);
        ss += __shfl_xor(ss, 8);
        ss += __shfl_xor(ss, 16);
        if ((lane & 31) == 0) sC2[row] = ss;
    }
    __syncthreads();
    if (tid < NK) {
        float s = Sg[tid] * LOG2E;
        sST[tid] = make_float2(s, s * sC2[tid]);
    }
    __syncthreads();   // sST visible before first (pre-[A]) softmax use

    f32x4 eacc[2][8];
    #pragma unroll
    for (int i = 0; i < 2; ++i)
        #pragma unroll
        for (int j = 0; j < 8; ++j)
            eacc[i][j] = (f32x4){0.f, 0.f, 0.f, 0.f};
    f32x4 cntacc[2];
    cntacc[0] = (f32x4){0.f, 0.f, 0.f, 0.f};
    cntacc[1] = (f32x4){0.f, 0.f, 0.f, 0.f};

    CU one8;
    #pragma unroll
    for (int j = 0; j < 8; ++j) one8.u[j] = 0x3F80;  // bf16 1.0

    #pragma unroll 1
    for (int t = 0; t < TT; ++t) {
        const int chunk = bg * TT + t;
        const float* rp = Xb + (size_t)(chunk * NC + rloc) * ND;

        // ---- convert full row from raw[] (registers only) ----
        CU cu[4];
        float x2 = 0.f;
        #pragma unroll
        for (int ks = 0; ks < 4; ++ks) {
            float4 va = raw[ks * 2], vb = raw[ks * 2 + 1];
            x2 += va.x*va.x + va.y*va.y + va.z*va.z + va.w*va.w;
            x2 += vb.x*vb.x + vb.y*vb.y + vb.z*vb.z + vb.w*vb.w;
            cu[ks].b[0] = (__bf16)va.x; cu[ks].b[1] = (__bf16)va.y;
            cu[ks].b[2] = (__bf16)va.z; cu[ks].b[3] = (__bf16)va.w;
            cu[ks].b[4] = (__bf16)vb.x; cu[ks].b[5] = (__bf16)vb.y;
            cu[ks].b[6] = (__bf16)vb.z; cu[ks].b[7] = (__bf16)vb.w;
        }
        x2 += __shfl_xor(x2, 16);
        x2 += __shfl_xor(x2, 32);       // full X2 of row (chunk*64 + rloc)

        // ---- prefetch ENTIRE next chunk row (earliest possible issue) ----
        if (t + 1 < TT) {
            const float* rpn = rp + (size_t)NC * ND;
            #pragma unroll
            for (int ks = 0; ks < 4; ++ks) {
                raw[ks * 2]     = *reinterpret_cast<const float4*>(rpn + ks * 32 + quad * 8);
                raw[ks * 2 + 1] = *reinterpret_cast<const float4*>(rpn + ks * 32 + quad * 8 + 4);
            }
        }

        // ---- matmul1 (pre-barrier: needs only cu regs + sCb/sST, never
        //      rewritten): D^T[n][cw] = X x C^T.
        //      D-frag: lane holds (n = quad*4+r, cw = mt*16+l15).
        f32x4 dacc[8];
        #pragma unroll
        for (int mt = 0; mt < 8; ++mt) {
            f32x4 acc = (f32x4){0.f, 0.f, 0.f, 0.f};
            #pragma unroll
            for (int ks = 0; ks < 4; ++ks) {
                bf16x8 cf = *reinterpret_cast<const bf16x8*>(
                    &sCb[(mt * 16 + l15) * CBP + ks * 32 + quad * 8]);
                acc = __builtin_amdgcn_mfma_f32_16x16x32_bf16(cu[ks].v, cf, acc, 0, 0, 0);
            }
            dacc[mt] = acc;
        }

        // ---- softmax over cw (pre-barrier), NO max pass (S<=0 => exp<=1) ----
        float x2r0 = __shfl(x2, quad * 4 + 0);
        float x2r1 = __shfl(x2, quad * 4 + 1);
        float x2r2 = __shfl(x2, quad * 4 + 2);
        float x2r3 = __shfl(x2, quad * 4 + 3);
        float ls0 = 0.f, ls1 = 0.f, ls2 = 0.f, ls3 = 0.f;
        #pragma unroll
        for (int mt = 0; mt < 8; ++mt) {
            float2 sv = sST[mt * 16 + l15];   // broadcast across quads, conflict-free
            float e0 = __builtin_amdgcn_exp2f(sv.x * fmaf(-2.f, dacc[mt][0], x2r0) + sv.y);
            float e1 = __builtin_amdgcn_exp2f(sv.x * fmaf(-2.f, dacc[mt][1], x2r1) + sv.y);
            float e2 = __builtin_amdgcn_exp2f(sv.x * fmaf(-2.f, dacc[mt][2], x2r2) + sv.y);
            float e3 = __builtin_amdgcn_exp2f(sv.x * fmaf(-2.f, dacc[mt][3], x2r3) + sv.y);
            dacc[mt][0] = e0; dacc[mt][1] = e1;
            dacc[mt][2] = e2; dacc[mt][3] = e3;
            ls0 += e0; ls1 += e1; ls2 += e2; ls3 += e3;
        }
        // reduce over cw: l15 axis via xor-tree (masks 1,2,4,8 only)
        #pragma unroll
        for (int sh = 1; sh < 16; sh <<= 1) {
            ls0 += __shfl_xor(ls0, sh);
            ls1 += __shfl_xor(ls1, sh);
            ls2 += __shfl_xor(ls2, sh);
            ls3 += __shfl_xor(ls3, sh);
        }
        const float inv0 = 1.0f / ls0, inv1 = 1.0f / ls1;
        const float inv2 = 1.0f / ls2, inv3 = 1.0f / ls3;

        // ---- normalize + pack A to bf16 regs (pre-barrier; hh = 8 ushort4) ----
        HH4 hh[8];
        #pragma unroll
        for (int mt = 0; mt < 8; ++mt) {
            hh[mt].b[0] = (__bf16)(dacc[mt][0] * inv0);
            hh[mt].b[1] = (__bf16)(dacc[mt][1] * inv1);
            hh[mt].b[2] = (__bf16)(dacc[mt][2] * inv2);
            hh[mt].b[3] = (__bf16)(dacc[mt][3] * inv3);
        }

        __syncthreads();                // (A) prev chunk's matmul2 reads done

        // ---- minimal [A]->[B] window: scatter X^T + store A^T only ----
        #pragma unroll
        for (int ks = 0; ks < 4; ++ks) {
            #pragma unroll
            for (int j = 0; j < 8; ++j) {
                int d  = ks * 32 + quad * 8 + j;
                int rs = rloc ^ (((d >> 3) & 3) << 3);
                sXT[d * XTP + rs] = cu[ks].u[j];
            }
        }
        #pragma unroll
        for (int mt = 0; mt < 8; ++mt) {
            *reinterpret_cast<ushort4*>(
                &sAt[(mt * 16 + l15) * ATP + wave * 16 + quad * 4]) = hh[mt].s;
        }

        __syncthreads();                // (B) X^T and A^T visible to all waves

        // ---- matmul2: E[cw][d] += A x X, dt-outer so each b-frag is read
        //      ONCE and reused for both mt2 (b128 reads 32 -> 16/wave/chunk).
        bf16x8 a0[2], a1[2];
        #pragma unroll
        for (int mt2 = 0; mt2 < 2; ++mt2) {
            const int cwrow = wave * 32 + mt2 * 16 + l15;
            a0[mt2] = *reinterpret_cast<const bf16x8*>(&sAt[cwrow * ATP + quad * 8]);
            a1[mt2] = *reinterpret_cast<const bf16x8*>(&sAt[cwrow * ATP + 32 + quad * 8]);
            // count[cw] += sum_n A[cw][n]: B = ones -> D[row][col] indep of col
            cntacc[mt2] = __builtin_amdgcn_mfma_f32_16x16x32_bf16(a0[mt2], one8.v, cntacc[mt2], 0, 0, 0);
            cntacc[mt2] = __builtin_amdgcn_mfma_f32_16x16x32_bf16(a1[mt2], one8.v, cntacc[mt2], 0, 0, 0);
        }
        #pragma unroll
        for (int dt = 0; dt < 8; ++dt) {
            const int drow = dt * 16 + l15;
            const int sw = ((drow >> 3) & 3) << 3;
            const unsigned short* xp = &sXT[drow * XTP];
            bf16x8 b0 = *reinterpret_cast<const bf16x8*>(&xp[(quad * 8) ^ sw]);
            bf16x8 b1 = *reinterpret_cast<const bf16x8*>(&xp[(32 + quad * 8) ^ sw]);
            #pragma unroll
            for (int mt2 = 0; mt2 < 2; ++mt2) {
                eacc[mt2][dt] = __builtin_amdgcn_mfma_f32_16x16x32_bf16(a0[mt2], b0, eacc[mt2][dt], 0, 0, 0);
                eacc[mt2][dt] = __builtin_amdgcn_mfma_f32_16x16x32_bf16(a1[mt2], b1, eacc[mt2][dt], 0, 0, 0);
            }
        }
    }

    // ---- epilogue: bf16 partial (E_part - count*C) to private ws slice ----
    // cntacc[mt2][r] holds count for cw = wave*32+mt2*16+quad*4+r (all l15 lanes)
    unsigned short* P = Pg + (size_t)bid * (NK * ND);
    #pragma unroll
    for (int mt2 = 0; mt2 < 2; ++mt2) {
        #pragma unroll
        for (int r = 0; r < 4; ++r) {
            const int cw = wave * 32 + mt2 * 16 + quad * 4 + r;
            const float cc = cntacc[mt2][r];
            const float* crow = Cg + cw * ND;
            #pragma unroll
            for (int dt = 0; dt < 8; ++dt) {
                const int d = dt * 16 + l15;
                *reinterpret_cast<__bf16*>(&P[cw * ND + d]) =
                    (__bf16)(eacc[mt2][dt][r] - cc * crow[d]);
            }
        }
    }
}

// ---------------- kernel 2: partial reduction ----------------
// thread-per-float2; BPB=32 partials deep, fully unrolled.
__global__ __launch_bounds__(128) void vq_reduce(
    const unsigned short* __restrict__ Pg, float* __restrict__ Eg)
{
    const int g  = blockIdx.x * 128 + threadIdx.x;   // 0..65535
    const int b  = g >> 13;                          // 8192 float2 per batch
    const int i2 = g & 8191;
    const unsigned short* base = Pg + (size_t)(b * BPB) * (NK * ND) + i2 * 2;
    float a0 = 0.f, a1 = 0.f;
    #pragma unroll 32
    for (int j = 0; j < BPB; ++j) {
        ushort2 v = *reinterpret_cast<const ushort2*>(base + (size_t)j * (NK * ND));
        a0 += bf2f(v.x); a1 += bf2f(v.y);
    }
    float2 o; o.x = a0; o.y = a1;
    *reinterpret_cast<float2*>(Eg + (size_t)b * (NK * ND) + i2 * 2) = o;
}

extern "C" void kernel_launch(void* const* d_in, const int* in_sizes, int n_in,
                              void* d_out, int out_size, void* d_ws, size_t ws_size,
                              hipStream_t stream) {
    const float* X = (const float*)d_in[0];
    const float* C = (const float*)d_in[1];
    const float* S = (const float*)d_in[2];
    float* E = (float*)d_out;
    (void)n_in; (void)in_sizes; (void)out_size; (void)ws_size;

    // ws layout: bf16 partials, 256 * 16384 u16 = 8 MiB.
    unsigned short* P = (unsigned short*)d_ws;

    hipLaunchKernelGGL(vq_main,   dim3(8 * BPB), dim3(256), 0, stream, X, C, S, P);
    hipLaunchKernelGGL(vq_reduce, dim3(512),     dim3(128), 0, stream, P, E);
}

// Round 5
// 113.428 us; speedup vs baseline: 1.0051x; 1.0012x over previous
//
#include <hip/hip_runtime.h>

// Soft VQ encoding, fused bf16-MFMA implementation. Round 13.
//   X:(8,16384,128) fp32, C:(128,128) fp32, S:(128) fp32 -> E:(8,128,128) fp32
// r12 post-mortem: -0.45us (114.0->113.57); 1 block/CU did NOT regress =>
// throughput-bound on shared per-CU resource (LDS pipe), latency fully hidden.
// Session history: SQ_LDS_BANK_CONFLICT ~2.23M/dispatch never fixed.
// r13 (two DS-pipe cuts, both surgical):
//  (1) scatter conflict fix: XOR-8 swizzle collapses quads onto the SAME 8
//      banks (288*quad = 0 mod 32; xor only permutes within an 8-dword
//      window) -> 4-way write conflict on all 32 scatter b16s. Replace with
//      mod-64 ROTATION col = (n + 16*quad) & 63: +16*quad shifts 8 dwords
//      per quad -> 32 banks covered, conflict-free. Read side: one aligned
//      b128 per half at col (quad*8 + 16*qd(drow)) & 63 (inverse rotation).
//  (2) ls-reduce off the DS pipe: 16 __shfl_xor (ds_swizzle) -> 16 DPP ops
//      (quad_perm 0xB1/0x4E, row_ror:4 = 0x124, row_ror:8 = 0x128); VALU
//      has slack, LDS pipe is the binding resource.
//   predicted: dur 113.6 -> 111.5-112.5; WRITE_SIZE flat 262144KB;
//   absmax ~128 (re-association only). Null => structural floor, ROOFLINE.

#define NN   16384
#define ND   128
#define NK   128
#define NC   64        // rows per chunk
#define TT   8         // chunks per block
#define BPB  32        // blocks per batch (grid = 8*BPB = 256)
#define CBP  136       // sCb row stride (bf16 elems), 272B -> b128-aligned, 2-way banks
#define XTP  72        // X^T LDS row stride, 144B
#define ATP  72        // A^T LDS row stride, 144B
#define LOG2E 1.4426950408889634f

typedef __bf16 bf16x8 __attribute__((ext_vector_type(8)));
typedef float  f32x4  __attribute__((ext_vector_type(4)));

union CU  { __bf16 b[8]; unsigned short u[8]; bf16x8 v; };
union HH4 { __bf16 b[4]; ushort4 s; };

__device__ __forceinline__ float bf2f(unsigned short u) {
    return __uint_as_float(((unsigned int)u) << 16);
}

// row-of-16 sum via DPP (VALU pipe, not LDS): quad_perm xor1, xor2, ror4, ror8
template<int CTRL>
__device__ __forceinline__ float dpp_add(float x) {
    int yi = __builtin_amdgcn_update_dpp(
        0, __builtin_bit_cast(int, x), CTRL, 0xF, 0xF, true);
    return x + __builtin_bit_cast(float, yi);
}
__device__ __forceinline__ float row16_sum(float x) {
    x = dpp_add<0xB1>(x);    // quad_perm [1,0,3,2]  (xor 1)
    x = dpp_add<0x4E>(x);    // quad_perm [2,3,0,1]  (xor 2)
    x = dpp_add<0x124>(x);   // row_ror:4
    x = dpp_add<0x128>(x);   // row_ror:8
    return x;
}

// ---------------- kernel 1: fused main ----------------
__global__ __launch_bounds__(256, 2) void vq_main(
    const float* __restrict__ Xg, const float* __restrict__ Cg,
    const float* __restrict__ Sg, unsigned short* __restrict__ Pg)
{
    __shared__ __align__(16) unsigned short sCb[NK * CBP];   // 34816 B
    __shared__ __align__(16) unsigned short sXT[ND * XTP];   // 18432 B
    __shared__ __align__(16) unsigned short sAt[NK * ATP];   // 18432 B
    __shared__ __align__(16) float2 sST[NK];                 // 1 KB
    __shared__ __align__(16) float  sC2[NK];                 // 512 B

    const int tid  = threadIdx.x;
    const int lane = tid & 63;
    const int wave = tid >> 6;
    const int l15  = lane & 15;
    const int quad = lane >> 4;
    const int bid  = blockIdx.x;
    const int b    = bid >> 5;        // batch (BPB=32)
    const int bg   = bid & (BPB - 1); // block-in-batch

    const float* Xb = Xg + (size_t)b * (NN * ND);
    const int rloc = wave * 16 + l15;   // chunk-local row this lane stages
    const int cs   = (rloc + 16 * quad) & 63;  // rotated scatter column

    // software pipeline: raw[] holds the FULL next chunk row (8 float4)
    float4 raw[8];
    {
        const float* rp0 = Xb + (size_t)(bg * TT * NC + rloc) * ND;
        #pragma unroll
        for (int ks = 0; ks < 4; ++ks) {
            raw[ks * 2]     = *reinterpret_cast<const float4*>(rp0 + ks * 32 + quad * 8);
            raw[ks * 2 + 1] = *reinterpret_cast<const float4*>(rp0 + ks * 32 + quad * 8 + 4);
        }
    }

    // ---- prologue: stage C -> bf16 LDS, C2 row sums, ST = {S*log2e, S*C2*log2e} ----
    #pragma unroll
    for (int it = 0; it < 16; ++it) {
        int flat = it * 256 + tid;
        int row  = flat >> 5;          // 0..127
        int c4   = flat & 31;
        float4 v = reinterpret_cast<const float4*>(Cg)[row * 32 + c4];
        HH4 h;
        h.b[0] = (__bf16)v.x; h.b[1] = (__bf16)v.y;
        h.b[2] = (__bf16)v.z; h.b[3] = (__bf16)v.w;
        *reinterpret_cast<ushort4*>(&sCb[row * CBP + c4 * 4]) = h.s;
        float ss = v.x*v.x + v.y*v.y + v.z*v.z + v.w*v.w;
        ss += __shfl_xor(ss, 1);
        ss += __shfl_xor(ss, 2);
        ss += __shfl_xor(ss, 4);
        ss += __shfl_xor(ss, 8);
        ss += __shfl_xor(ss, 16);
        if ((lane & 31) == 0) sC2[row] = ss;
    }
    __syncthreads();
    if (tid < NK) {
        float s = Sg[tid] * LOG2E;
        sST[tid] = make_float2(s, s * sC2[tid]);
    }
    __syncthreads();   // sST visible before first (pre-[A]) softmax use

    f32x4 eacc[2][8];
    #pragma unroll
    for (int i = 0; i < 2; ++i)
        #pragma unroll
        for (int j = 0; j < 8; ++j)
            eacc[i][j] = (f32x4){0.f, 0.f, 0.f, 0.f};
    f32x4 cntacc[2];
    cntacc[0] = (f32x4){0.f, 0.f, 0.f, 0.f};
    cntacc[1] = (f32x4){0.f, 0.f, 0.f, 0.f};

    CU one8;
    #pragma unroll
    for (int j = 0; j < 8; ++j) one8.u[j] = 0x3F80;  // bf16 1.0

    #pragma unroll 1
    for (int t = 0; t < TT; ++t) {
        const int chunk = bg * TT + t;
        const float* rp = Xb + (size_t)(chunk * NC + rloc) * ND;

        // ---- convert full row from raw[] (registers only) ----
        CU cu[4];
        float x2 = 0.f;
        #pragma unroll
        for (int ks = 0; ks < 4; ++ks) {
            float4 va = raw[ks * 2], vb = raw[ks * 2 + 1];
            x2 += va.x*va.x + va.y*va.y + va.z*va.z + va.w*va.w;
            x2 += vb.x*vb.x + vb.y*vb.y + vb.z*vb.z + vb.w*vb.w;
            cu[ks].b[0] = (__bf16)va.x; cu[ks].b[1] = (__bf16)va.y;
            cu[ks].b[2] = (__bf16)va.z; cu[ks].b[3] = (__bf16)va.w;
            cu[ks].b[4] = (__bf16)vb.x; cu[ks].b[5] = (__bf16)vb.y;
            cu[ks].b[6] = (__bf16)vb.z; cu[ks].b[7] = (__bf16)vb.w;
        }
        x2 += __shfl_xor(x2, 16);
        x2 += __shfl_xor(x2, 32);       // full X2 of row (chunk*64 + rloc)

        // ---- prefetch ENTIRE next chunk row (earliest possible issue) ----
        if (t + 1 < TT) {
            const float* rpn = rp + (size_t)NC * ND;
            #pragma unroll
            for (int ks = 0; ks < 4; ++ks) {
                raw[ks * 2]     = *reinterpret_cast<const float4*>(rpn + ks * 32 + quad * 8);
                raw[ks * 2 + 1] = *reinterpret_cast<const float4*>(rpn + ks * 32 + quad * 8 + 4);
            }
        }

        // ---- matmul1 (pre-barrier): D^T[n][cw] = X x C^T ----
        // D-frag: lane holds (n = quad*4+r, cw = mt*16+l15).
        f32x4 dacc[8];
        #pragma unroll
        for (int mt = 0; mt < 8; ++mt) {
            f32x4 acc = (f32x4){0.f, 0.f, 0.f, 0.f};
            #pragma unroll
            for (int ks = 0; ks < 4; ++ks) {
                bf16x8 cf = *reinterpret_cast<const bf16x8*>(
                    &sCb[(mt * 16 + l15) * CBP + ks * 32 + quad * 8]);
                acc = __builtin_amdgcn_mfma_f32_16x16x32_bf16(cu[ks].v, cf, acc, 0, 0, 0);
            }
            dacc[mt] = acc;
        }

        // ---- softmax over cw (pre-barrier), NO max pass (S<=0 => exp<=1) ----
        float x2r0 = __shfl(x2, quad * 4 + 0);
        float x2r1 = __shfl(x2, quad * 4 + 1);
        float x2r2 = __shfl(x2, quad * 4 + 2);
        float x2r3 = __shfl(x2, quad * 4 + 3);
        float ls0 = 0.f, ls1 = 0.f, ls2 = 0.f, ls3 = 0.f;
        #pragma unroll
        for (int mt = 0; mt < 8; ++mt) {
            float2 sv = sST[mt * 16 + l15];   // broadcast across quads, conflict-free
            float e0 = __builtin_amdgcn_exp2f(sv.x * fmaf(-2.f, dacc[mt][0], x2r0) + sv.y);
            float e1 = __builtin_amdgcn_exp2f(sv.x * fmaf(-2.f, dacc[mt][1], x2r1) + sv.y);
            float e2 = __builtin_amdgcn_exp2f(sv.x * fmaf(-2.f, dacc[mt][2], x2r2) + sv.y);
            float e3 = __builtin_amdgcn_exp2f(sv.x * fmaf(-2.f, dacc[mt][3], x2r3) + sv.y);
            dacc[mt][0] = e0; dacc[mt][1] = e1;
            dacc[mt][2] = e2; dacc[mt][3] = e3;
            ls0 += e0; ls1 += e1; ls2 += e2; ls3 += e3;
        }
        // reduce over cw's l15 axis: DPP row-of-16 sum (VALU pipe, not LDS)
        ls0 = row16_sum(ls0);
        ls1 = row16_sum(ls1);
        ls2 = row16_sum(ls2);
        ls3 = row16_sum(ls3);
        const float inv0 = 1.0f / ls0, inv1 = 1.0f / ls1;
        const float inv2 = 1.0f / ls2, inv3 = 1.0f / ls3;

        // ---- normalize + pack A to bf16 regs (pre-barrier; hh = 8 ushort4) ----
        HH4 hh[8];
        #pragma unroll
        for (int mt = 0; mt < 8; ++mt) {
            hh[mt].b[0] = (__bf16)(dacc[mt][0] * inv0);
            hh[mt].b[1] = (__bf16)(dacc[mt][1] * inv1);
            hh[mt].b[2] = (__bf16)(dacc[mt][2] * inv2);
            hh[mt].b[3] = (__bf16)(dacc[mt][3] * inv3);
        }

        __syncthreads();                // (A) prev chunk's matmul2 reads done

        // ---- minimal [A]->[B] window: scatter X^T + store A^T only ----
        // rotated column cs = (rloc + 16*quad) & 63: conflict-free writes
        #pragma unroll
        for (int ks = 0; ks < 4; ++ks) {
            #pragma unroll
            for (int j = 0; j < 8; ++j) {
                int d = ks * 32 + quad * 8 + j;
                sXT[d * XTP + cs] = cu[ks].u[j];
            }
        }
        #pragma unroll
        for (int mt = 0; mt < 8; ++mt) {
            *reinterpret_cast<ushort4*>(
                &sAt[(mt * 16 + l15) * ATP + wave * 16 + quad * 4]) = hh[mt].s;
        }

        __syncthreads();                // (B) X^T and A^T visible to all waves

        // ---- matmul2: E[cw][d] += A x X, dt-outer so each b-frag is read
        //      ONCE and reused for both mt2.
        bf16x8 a0[2], a1[2];
        #pragma unroll
        for (int mt2 = 0; mt2 < 2; ++mt2) {
            const int cwrow = wave * 32 + mt2 * 16 + l15;
            a0[mt2] = *reinterpret_cast<const bf16x8*>(&sAt[cwrow * ATP + quad * 8]);
            a1[mt2] = *reinterpret_cast<const bf16x8*>(&sAt[cwrow * ATP + 32 + quad * 8]);
            // count[cw] += sum_n A[cw][n]: B = ones -> D[row][col] indep of col
            cntacc[mt2] = __builtin_amdgcn_mfma_f32_16x16x32_bf16(a0[mt2], one8.v, cntacc[mt2], 0, 0, 0);
            cntacc[mt2] = __builtin_amdgcn_mfma_f32_16x16x32_bf16(a1[mt2], one8.v, cntacc[mt2], 0, 0, 0);
        }
        #pragma unroll
        for (int dt = 0; dt < 8; ++dt) {
            const int drow = dt * 16 + l15;
            const int qd = (drow >> 3) & 3;            // writer quad of this row
            const unsigned short* xp = &sXT[drow * XTP];
            bf16x8 b0 = *reinterpret_cast<const bf16x8*>(
                &xp[(quad * 8 + 16 * qd) & 63]);
            bf16x8 b1 = *reinterpret_cast<const bf16x8*>(
                &xp[(32 + quad * 8 + 16 * qd) & 63]);
            #pragma unroll
            for (int mt2 = 0; mt2 < 2; ++mt2) {
                eacc[mt2][dt] = __builtin_amdgcn_mfma_f32_16x16x32_bf16(a0[mt2], b0, eacc[mt2][dt], 0, 0, 0);
                eacc[mt2][dt] = __builtin_amdgcn_mfma_f32_16x16x32_bf16(a1[mt2], b1, eacc[mt2][dt], 0, 0, 0);
            }
        }
    }

    // ---- epilogue: bf16 partial (E_part - count*C) to private ws slice ----
    unsigned short* P = Pg + (size_t)bid * (NK * ND);
    #pragma unroll
    for (int mt2 = 0; mt2 < 2; ++mt2) {
        #pragma unroll
        for (int r = 0; r < 4; ++r) {
            const int cw = wave * 32 + mt2 * 16 + quad * 4 + r;
            const float cc = cntacc[mt2][r];
            const float* crow = Cg + cw * ND;
            #pragma unroll
            for (int dt = 0; dt < 8; ++dt) {
                const int d = dt * 16 + l15;
                *reinterpret_cast<__bf16*>(&P[cw * ND + d]) =
                    (__bf16)(eacc[mt2][dt][r] - cc * crow[d]);
            }
        }
    }
}

// ---------------- kernel 2: partial reduction ----------------
// thread-per-float2; BPB=32 partials deep, fully unrolled.
__global__ __launch_bounds__(128) void vq_reduce(
    const unsigned short* __restrict__ Pg, float* __restrict__ Eg)
{
    const int g  = blockIdx.x * 128 + threadIdx.x;   // 0..65535
    const int b  = g >> 13;                          // 8192 float2 per batch
    const int i2 = g & 8191;
    const unsigned short* base = Pg + (size_t)(b * BPB) * (NK * ND) + i2 * 2;
    float a0 = 0.f, a1 = 0.f;
    #pragma unroll 32
    for (int j = 0; j < BPB; ++j) {
        ushort2 v = *reinterpret_cast<const ushort2*>(base + (size_t)j * (NK * ND));
        a0 += bf2f(v.x); a1 += bf2f(v.y);
    }
    float2 o; o.x = a0; o.y = a1;
    *reinterpret_cast<float2*>(Eg + (size_t)b * (NK * ND) + i2 * 2) = o;
}

extern "C" void kernel_launch(void* const* d_in, const int* in_sizes, int n_in,
                              void* d_out, int out_size, void* d_ws, size_t ws_size,
                              hipStream_t stream) {
    const float* X = (const float*)d_in[0];
    const float* C = (const float*)d_in[1];
    const float* S = (const float*)d_in[2];
    float* E = (float*)d_out;
    (void)n_in; (void)in_sizes; (void)out_size; (void)ws_size;

    // ws layout: bf16 partials, 256 * 16384 u16 = 8 MiB.
    unsigned short* P = (unsigned short*)d_ws;

    hipLaunchKernelGGL(vq_main,   dim3(8 * BPB), dim3(256), 0, stream, X, C, S, P);
    hipLaunchKernelGGL(vq_reduce, dim3(512),     dim3(128), 0, stream, P, E);
}